// Round 7
// baseline (24052.655 us; speedup 1.0000x reference)
//
#include <hip/hip_runtime.h>

typedef _Float16 f16;
typedef _Float16 f16x8 __attribute__((ext_vector_type(8)));
typedef float    f32x4 __attribute__((ext_vector_type(4)));
typedef unsigned int u32x4 __attribute__((ext_vector_type(4)));

static __device__ __forceinline__ f16x8 asf16x8(u32x4 v) {
  return __builtin_bit_cast(f16x8, v);
}

struct PtrPack { const float* p[8]; };

#define MFMA16(A, B, C) __builtin_amdgcn_mfma_f32_16x16x32_f16((A), (B), (C), 0, 0, 0)

// ---------------- prep A: 4x Wx (256x256) fp32 [k][u] -> f16 [u][k] for the GEMM ----
__global__ __launch_bounds__(256) void k_prep(PtrPack pp, f16* __restrict__ wxT) {
  int m = blockIdx.z, kt = blockIdx.y, ut = blockIdx.x;
  const float* src = pp.p[m];
  f16* dst = wxT + m * 65536;
  __shared__ f16 tile[64][66];
  int c = threadIdx.x & 63, r0 = threadIdx.x >> 6;
#pragma unroll
  for (int i = 0; i < 16; ++i) {
    int r = i * 4 + r0;
    tile[c][r] = (f16)src[(kt * 64 + r) * 256 + ut * 64 + c];
  }
  __syncthreads();
#pragma unroll
  for (int i = 0; i < 16; ++i) {
    int ul = i * 4 + r0;
    dst[(size_t)(ut * 64 + ul) * 256 + kt * 64 + c] = tile[ul][c];
  }
}

// ---------------- prep F: 4x Wh fp32 [k][u] -> MFMA B-fragment-major f16 -------------
// frag(ct,kt): 64 lanes x 16B; lane l holds Wh[k=kt*32+(l>>4)*8+e][col=ct*16+(l&15)].
__global__ __launch_bounds__(256) void k_prepF(PtrPack pp, u32x4* __restrict__ fragB) {
  int kb = blockIdx.x;   // k-block of 64 (0..3)
  int m  = blockIdx.y;   // gate 0..3 = i,f,g,o
  const float* src = pp.p[4 + m];
  int u = threadIdx.x;
  int ct = m * 16 + (u >> 4), cl = u & 15;
#pragma unroll
  for (int q = 0; q < 2; ++q) {
    int kt = kb * 2 + q;
#pragma unroll
    for (int l16 = 0; l16 < 4; ++l16) {
      union { f16 h[8]; u32x4 v; } pk;
#pragma unroll
      for (int e = 0; e < 8; ++e)
        pk.h[e] = (f16)src[(size_t)(kt * 32 + l16 * 8 + e) * 256 + u];
      fragB[(size_t)((ct * 8 + kt) * 64 + l16 * 16 + cl)] = pk.v;
    }
  }
}

// ---------------- X-part GEMM: XW (f16, layout [t][b][u][gate]) ----------------------
__global__ __launch_bounds__(256) void k_gemm(const float* __restrict__ X,
                                              const f16* __restrict__ wxT,
                                              f16* __restrict__ xw, int chunk0) {
  int nblk = blockIdx.x;  // gate
  int mblk = blockIdx.y;
  int b    = blockIdx.z;
  __shared__ f16 Alds[64][48];
  __shared__ f16 Blds[256][48];
  int tid = threadIdx.x, wave = tid >> 6, lane = tid & 63;
  int l15 = lane & 15, l4 = lane >> 4;
  f32x4 acc[16];
#pragma unroll
  for (int i = 0; i < 16; ++i) acc[i] = (f32x4){0.f, 0.f, 0.f, 0.f};
  const float* Xb = X + ((size_t)b * 2048 + chunk0 + mblk * 64) * 256;
  const f16*   Bb = wxT + (size_t)nblk * 256 * 256;
  int arow = tid >> 2, akq = (tid & 3) * 8;

  for (int kk = 0; kk < 8; ++kk) {
    {
      const float* s = Xb + arow * 256 + kk * 32 + akq;
      float4 v0 = *(const float4*)s;
      float4 v1 = *(const float4*)(s + 4);
      union { f16 h[8]; uint4 q; } uq;
      uq.h[0] = (f16)v0.x; uq.h[1] = (f16)v0.y; uq.h[2] = (f16)v0.z; uq.h[3] = (f16)v0.w;
      uq.h[4] = (f16)v1.x; uq.h[5] = (f16)v1.y; uq.h[6] = (f16)v1.z; uq.h[7] = (f16)v1.w;
      *(uint4*)(&Alds[arow][akq]) = uq.q;
    }
    {
      const uint4* s = (const uint4*)(Bb + (size_t)tid * 256 + kk * 32);
      uint4* d = (uint4*)(&Blds[tid][0]);
      d[0] = s[0]; d[1] = s[1]; d[2] = s[2]; d[3] = s[3];
    }
    __syncthreads();
    f16x8 a = *(const f16x8*)(&Alds[wave * 16 + l15][l4 * 8]);
#pragma unroll
    for (int nt = 0; nt < 16; ++nt) {
      f16x8 bb = *(const f16x8*)(&Blds[nt * 16 + l15][l4 * 8]);
      acc[nt] = MFMA16(a, bb, acc[nt]);
    }
    __syncthreads();
  }
#pragma unroll
  for (int nt = 0; nt < 16; ++nt) {
#pragma unroll
    for (int r = 0; r < 4; ++r) {
      int trow = mblk * 64 + wave * 16 + l4 * 4 + r;
      int ucol = nt * 16 + l15;
      xw[((size_t)trow * 64 + b) * 1024 + ucol * 4 + nblk] = (f16)acc[nt][r];
    }
  }
}

// ---------------- recurrent kernel: MFMA h-matmul, 1 wg/batch, 512 thr ---------------
// Wave w owns units [w*32, w*32+32); col-tiles ct = G*16 + w*2 + d.
// Delivery: i,f gates AGPR-resident (128 AGPR/thread via "a" pins);
//           o(d=0) LDS-resident (64KB); o(d=1) + g streamed from L2 (192KB/step).
__global__ __launch_bounds__(512, 2) void k_rnn(
    const f16* __restrict__ xw, const u32x4* __restrict__ fragB,
    const float* __restrict__ bi, const float* __restrict__ bf_,
    const float* __restrict__ bg, const float* __restrict__ bo,
    float* __restrict__ out, float* __restrict__ hstate, float* __restrict__ cstate,
    int chunk0, int chunk_len) {
  extern __shared__ char smem[];
  u32x4* WO = (u32x4*)smem;                                  // [8w][8kt][64] 64KB: o d=0
  unsigned short* hb = (unsigned short*)(smem + 65536);      // [2][256]
  int b = blockIdx.x;
  int tid = threadIdx.x;
  int w = tid >> 6, lane = tid & 63;
  int ul = lane & 31;
  int u = w * 32 + ul;
  bool act = lane < 32;

  // gates i,f -> AGPR-resident fragments [d*8+kt]
  u32x4 RI[16], RF[16];
#pragma unroll
  for (int d = 0; d < 2; ++d)
#pragma unroll
    for (int kt = 0; kt < 8; ++kt) {
      RI[d * 8 + kt] = fragB[(size_t)((( 0 + w * 2 + d) * 8 + kt) * 64 + lane)];
      RF[d * 8 + kt] = fragB[(size_t)(((16 + w * 2 + d) * 8 + kt) * 64 + lane)];
    }
  // o-gate d=0 -> LDS
#pragma unroll
  for (int kt = 0; kt < 8; ++kt)
    WO[(w * 8 + kt) * 64 + lane] = fragB[(size_t)(((48 + w * 2) * 8 + kt) * 64 + lane)];

  float B0 = bi[u], B1 = bf_[u], B2 = bg[u], B3 = bo[u];
  float c, hcur;
  if (chunk0 == 0) { c = 0.f; hcur = 0.f; }
  else { c = cstate[b * 256 + u]; hcur = hstate[b * 256 + u]; }
  if (act) hb[u] = __builtin_bit_cast(unsigned short, (f16)hcur);
  __syncthreads();

  const u32x4* pG0 = fragB + (size_t)(((32 + w * 2 + 0) * 8) * 64 + lane);  // g d=0
  const u32x4* pG1 = fragB + (size_t)(((32 + w * 2 + 1) * 8) * 64 + lane);  // g d=1
  const u32x4* pO1 = fragB + (size_t)(((48 + w * 2 + 1) * 8) * 64 + lane);  // o d=1

  int p = 0;
#pragma unroll 1
  for (int t = 0; t < chunk_len; ++t) {
    // keep i,f resident in AGPRs (hard pin each iteration; empty asm, zero insts)
#pragma unroll
    for (int j = 0; j < 16; ++j) {
      asm volatile("" : "+a"(RI[j]));
      asm volatile("" : "+a"(RF[j]));
    }
    // x-part (8B coalesced per lane)
    ushort4 xv = *(const ushort4*)(xw + ((size_t)t * 64 + b) * 1024 + u * 4);
    // A fragments from h (LDS broadcast): lane reads h[kt*32 + (l>>4)*8 ..+8]
    u32x4 A[8];
    {
      const unsigned short* hbp = hb + p * 256 + (lane >> 4) * 8;
#pragma unroll
      for (int kt = 0; kt < 8; ++kt) A[kt] = *(const u32x4*)(hbp + kt * 32);
    }
    // stream g d=0 (hides under i-MFMAs)
    u32x4 SG[8];
#pragma unroll
    for (int kt = 0; kt < 8; ++kt) SG[kt] = pG0[kt * 64];

    f32x4 ai0 = {0.f,0.f,0.f,0.f}, ai1 = {0.f,0.f,0.f,0.f};
#pragma unroll
    for (int kt = 0; kt < 8; ++kt) {
      ai0 = MFMA16(asf16x8(A[kt]), asf16x8(RI[kt]), ai0);
      ai1 = MFMA16(asf16x8(A[kt]), asf16x8(RI[8 + kt]), ai1);
    }
    float gi0 = ai0[0], gi1 = ai1[0];
    // read o d=0 from LDS (hides under f-MFMAs)
    u32x4 SO[8];
#pragma unroll
    for (int kt = 0; kt < 8; ++kt) SO[kt] = WO[(w * 8 + kt) * 64 + lane];

    f32x4 af0 = {0.f,0.f,0.f,0.f}, af1 = {0.f,0.f,0.f,0.f};
#pragma unroll
    for (int kt = 0; kt < 8; ++kt) {
      af0 = MFMA16(asf16x8(A[kt]), asf16x8(RF[kt]), af0);
      af1 = MFMA16(asf16x8(A[kt]), asf16x8(RF[8 + kt]), af1);
    }
    float gf0 = af0[0], gf1 = af1[0];

    // g d=0 MFMAs (SG arrives by now), then reuse SG for g d=1 stream
    f32x4 ag0 = {0.f,0.f,0.f,0.f};
#pragma unroll
    for (int kt = 0; kt < 8; ++kt) ag0 = MFMA16(asf16x8(A[kt]), asf16x8(SG[kt]), ag0);
    float gg0 = ag0[0];
#pragma unroll
    for (int kt = 0; kt < 8; ++kt) SG[kt] = pG1[kt * 64];

    // o d=0 MFMAs, then stream o d=1 into SO
    f32x4 ao0 = {0.f,0.f,0.f,0.f};
#pragma unroll
    for (int kt = 0; kt < 8; ++kt) ao0 = MFMA16(asf16x8(A[kt]), asf16x8(SO[kt]), ao0);
    float go0 = ao0[0];
#pragma unroll
    for (int kt = 0; kt < 8; ++kt) SO[kt] = pO1[kt * 64];

    f32x4 ag1 = {0.f,0.f,0.f,0.f};
#pragma unroll
    for (int kt = 0; kt < 8; ++kt) ag1 = MFMA16(asf16x8(A[kt]), asf16x8(SG[kt]), ag1);
    float gg1 = ag1[0];
    f32x4 ao1 = {0.f,0.f,0.f,0.f};
#pragma unroll
    for (int kt = 0; kt < 8; ++kt) ao1 = MFMA16(asf16x8(A[kt]), asf16x8(SO[kt]), ao1);
    float go1 = ao1[0];

    // in-wave epilogue: lanes 0..31 own unit u = w*32 + ul; d-select via lane bit 4
    bool dsel = (lane & 16) != 0;
    float xi = (float)__builtin_bit_cast(f16, xv.x);
    float xf = (float)__builtin_bit_cast(f16, xv.y);
    float xg = (float)__builtin_bit_cast(f16, xv.z);
    float xo = (float)__builtin_bit_cast(f16, xv.w);
    float pi_ = (dsel ? gi1 : gi0) + xi + B0;
    float pf_ = (dsel ? gf1 : gf0) + xf + B1;
    float pg_ = (dsel ? gg1 : gg0) + xg + B2;
    float po_ = (dsel ? go1 : go0) + xo + B3;
    float Gi = 1.f / (1.f + __expf(-pi_));
    float Gf = 1.f / (1.f + __expf(-pf_));
    float e2 = __expf(-2.f * fabsf(pg_));
    float Gg = copysignf((1.f - e2) / (1.f + e2), pg_);
    float Go = 1.f / (1.f + __expf(-po_));
    c = Gf * c + Gi * Gg;
    float ec = __expf(-2.f * fabsf(c));
    float tc = copysignf((1.f - ec) / (1.f + ec), c);
    float h = Go * tc;
    hcur = h;
    int gt = chunk0 + t;
    if (act) {
      out[((size_t)b * 2048 + gt) * 256 + u] = h;
      hb[(p ^ 1) * 256 + u] = __builtin_bit_cast(unsigned short, (f16)h);
      if (gt == 2047) {
        out[33554432 + b * 256 + u] = h;
        out[33554432 + 16384 + b * 256 + u] = c;
      }
    }
    __syncthreads();
    p ^= 1;
  }
  if ((chunk0 + chunk_len < 2048) && act) {
    hstate[b * 256 + u] = hcur;
    cstate[b * 256 + u] = c;
  }
}

extern "C" void kernel_launch(void* const* d_in, const int* in_sizes, int n_in,
                              void* d_out, int out_size, void* d_ws, size_t ws_size,
                              hipStream_t stream) {
  const float* X = (const float*)d_in[0];
  // dict order: X, W_ii, W_hi, b_i, W_if, W_hf, b_f, W_ig, W_hg, b_g, W_io, W_ho, b_o
  PtrPack pp;
  pp.p[0] = (const float*)d_in[1];   // W_ii
  pp.p[1] = (const float*)d_in[4];   // W_if
  pp.p[2] = (const float*)d_in[7];   // W_ig
  pp.p[3] = (const float*)d_in[10];  // W_io
  pp.p[4] = (const float*)d_in[2];   // W_hi
  pp.p[5] = (const float*)d_in[5];   // W_hf
  pp.p[6] = (const float*)d_in[8];   // W_hg
  pp.p[7] = (const float*)d_in[11];  // W_ho
  const float* bi  = (const float*)d_in[3];
  const float* bf_ = (const float*)d_in[6];
  const float* bg  = (const float*)d_in[9];
  const float* bo  = (const float*)d_in[12];
  float* out = (float*)d_out;

  char* ws = (char*)d_ws;
  f16*   wxT    = (f16*)ws;                       // 524288 B
  u32x4* fragB  = (u32x4*)(ws + 524288);          // 524288 B (64 ct x 8 kt x 1KB)
  float* hstate = (float*)(ws + 1048576);         // 65536 B
  float* cstate = (float*)(ws + 1114112);         // 65536 B
  f16*   xwbuf  = (f16*)(ws + 1179648);           // S_c * 64 * 1024 * 2 B

  long avail = (ws_size > 1310720) ? (long)(ws_size - 1310720) : 0;
  long sc = avail / 131072;
  sc = (sc / 64) * 64;
  if (sc < 64) sc = 64;
  if (sc > 2048) sc = 2048;

  static const int RNN_SMEM = 65536 + 1024;
  hipFuncSetAttribute((const void*)k_rnn, hipFuncAttributeMaxDynamicSharedMemorySize,
                      RNN_SMEM);

  k_prep<<<dim3(4, 4, 4), 256, 0, stream>>>(pp, wxT);
  k_prepF<<<dim3(4, 4), 256, 0, stream>>>(pp, fragB);

  for (int s0 = 0; s0 < 2048; s0 += (int)sc) {
    int len = (int)((2048 - s0) < sc ? (2048 - s0) : sc);
    k_gemm<<<dim3(4, len / 64, 64), 256, 0, stream>>>(X, wxT, xwbuf, s0);
    k_rnn<<<dim3(64), 512, RNN_SMEM, stream>>>(xwbuf, fragB, bi, bf_, bg, bo, out,
                                               hstate, cstate, s0, len);
  }
}

// Round 8
// 4328.839 us; speedup vs baseline: 5.5564x; 5.5564x over previous
//
#include <hip/hip_runtime.h>

typedef _Float16 f16;
typedef _Float16 f16x8 __attribute__((ext_vector_type(8)));
typedef float    f32x4 __attribute__((ext_vector_type(4)));
typedef unsigned int u32x4 __attribute__((ext_vector_type(4)));

static __device__ __forceinline__ f16x8 asf16x8(u32x4 v) {
  return __builtin_bit_cast(f16x8, v);
}
static __device__ __forceinline__ float tof(unsigned short x) {
  return (float)__builtin_bit_cast(f16, x);
}

struct PtrPack { const float* p[8]; };

#define MFMA16(A, B, C) __builtin_amdgcn_mfma_f32_16x16x32_f16((A), (B), (C), 0, 0, 0)

// ---------------- prep A: 4x Wx (256x256) fp32 [k][u] -> f16 [u][k] for the GEMM ----
__global__ __launch_bounds__(256) void k_prep(PtrPack pp, f16* __restrict__ wxT) {
  int m = blockIdx.z, kt = blockIdx.y, ut = blockIdx.x;
  const float* src = pp.p[m];
  f16* dst = wxT + m * 65536;
  __shared__ f16 tile[64][66];
  int c = threadIdx.x & 63, r0 = threadIdx.x >> 6;
#pragma unroll
  for (int i = 0; i < 16; ++i) {
    int r = i * 4 + r0;
    tile[c][r] = (f16)src[(kt * 64 + r) * 256 + ut * 64 + c];
  }
  __syncthreads();
#pragma unroll
  for (int i = 0; i < 16; ++i) {
    int ul = i * 4 + r0;
    dst[(size_t)(ut * 64 + ul) * 256 + kt * 64 + c] = tile[ul][c];
  }
}

// ---------------- prep F: 4x Wh fp32 [k][u] -> MFMA B-fragment-major f16 -------------
// frag(ct,kt): 64 lanes x 16B; lane l holds Wh[k=kt*32+(l>>4)*8+e][col=ct*16+(l&15)].
__global__ __launch_bounds__(256) void k_prepF(PtrPack pp, u32x4* __restrict__ fragB) {
  int kb = blockIdx.x;   // k-block of 64 (0..3)
  int m  = blockIdx.y;   // gate 0..3 = i,f,g,o
  const float* src = pp.p[4 + m];
  int u = threadIdx.x;
  int ct = m * 16 + (u >> 4), cl = u & 15;
#pragma unroll
  for (int q = 0; q < 2; ++q) {
    int kt = kb * 2 + q;
#pragma unroll
    for (int l16 = 0; l16 < 4; ++l16) {
      union { f16 h[8]; u32x4 v; } pk;
#pragma unroll
      for (int e = 0; e < 8; ++e)
        pk.h[e] = (f16)src[(size_t)(kt * 32 + l16 * 8 + e) * 256 + u];
      fragB[(size_t)((ct * 8 + kt) * 64 + l16 * 16 + cl)] = pk.v;
    }
  }
}

// ---------------- X-part GEMM: XW (f16, layout [t][b][u][gate]) ----------------------
__global__ __launch_bounds__(256) void k_gemm(const float* __restrict__ X,
                                              const f16* __restrict__ wxT,
                                              f16* __restrict__ xw, int chunk0,
                                              int len) {
  int nblk = blockIdx.x;  // gate
  int mblk = blockIdx.y;
  int b    = blockIdx.z;
  __shared__ f16 Alds[64][48];
  __shared__ f16 Blds[256][48];
  int tid = threadIdx.x, wave = tid >> 6, lane = tid & 63;
  int l15 = lane & 15, l4 = lane >> 4;
  f32x4 acc[16];
#pragma unroll
  for (int i = 0; i < 16; ++i) acc[i] = (f32x4){0.f, 0.f, 0.f, 0.f};
  int tg = chunk0 + mblk * 64 + (tid >> 2);
  if (tg > 2047) tg = 2047;  // clamp (ragged tail) -- rows >= len never read
  const float* Xrow = X + ((size_t)b * 2048 + tg) * 256;
  const f16*   Bb = wxT + (size_t)nblk * 256 * 256;
  int arow = tid >> 2, akq = (tid & 3) * 8;

  for (int kk = 0; kk < 8; ++kk) {
    {
      const float* s = Xrow + kk * 32 + akq;
      float4 v0 = *(const float4*)s;
      float4 v1 = *(const float4*)(s + 4);
      union { f16 h[8]; uint4 q; } uq;
      uq.h[0] = (f16)v0.x; uq.h[1] = (f16)v0.y; uq.h[2] = (f16)v0.z; uq.h[3] = (f16)v0.w;
      uq.h[4] = (f16)v1.x; uq.h[5] = (f16)v1.y; uq.h[6] = (f16)v1.z; uq.h[7] = (f16)v1.w;
      *(uint4*)(&Alds[arow][akq]) = uq.q;
    }
    {
      const uint4* s = (const uint4*)(Bb + (size_t)tid * 256 + kk * 32);
      uint4* d = (uint4*)(&Blds[tid][0]);
      d[0] = s[0]; d[1] = s[1]; d[2] = s[2]; d[3] = s[3];
    }
    __syncthreads();
    f16x8 a = *(const f16x8*)(&Alds[wave * 16 + l15][l4 * 8]);
#pragma unroll
    for (int nt = 0; nt < 16; ++nt) {
      f16x8 bb = *(const f16x8*)(&Blds[nt * 16 + l15][l4 * 8]);
      acc[nt] = MFMA16(a, bb, acc[nt]);
    }
    __syncthreads();
  }
#pragma unroll
  for (int nt = 0; nt < 16; ++nt) {
#pragma unroll
    for (int r = 0; r < 4; ++r) {
      int trow = mblk * 64 + wave * 16 + l4 * 4 + r;
      int ucol = nt * 16 + l15;
      if (trow < len)
        xw[((size_t)trow * 64 + b) * 1024 + ucol * 4 + nblk] = (f16)acc[nt][r];
    }
  }
}

// ---------------- recurrent kernel: 2 wgs/batch (unit-split), MFMA, h-exchange -------
// wg j owns units [j*128, j*128+128), ALL 4 gates for them. Per wave (8 waves): one
// 16-col unit-tile V=j*8+w; gates i,g LDS-resident (128KB), f,o streamed from L2.
// Cross-wg: only h (128 x f16) exchanged per step via device-scope u32 atomics,
// payload (tag16|h16), parity-double-buffered slots (deadlock-free; see analysis).
__global__ __launch_bounds__(512, 2) void k_rnn(
    const f16* __restrict__ xw, const u32x4* __restrict__ fragB,
    const float* __restrict__ bi, const float* __restrict__ bf_,
    const float* __restrict__ bg, const float* __restrict__ bo,
    float* __restrict__ out, float* __restrict__ hstate, float* __restrict__ cstate,
    unsigned int* __restrict__ XB, int chunk0, int chunk_len) {
  extern __shared__ char smem[];
  u32x4* WL = (u32x4*)smem;                               // [8w][2m][8kt][64] 128KB
  unsigned short* hb = (unsigned short*)(smem + 131072);  // [2][256]
  int b = blockIdx.x & 63;
  int j = blockIdx.x >> 6;
  int tid = threadIdx.x, w = tid >> 6, lane = tid & 63;
  int cl = lane & 15;
  int V = j * 8 + w;          // global unit-tile of this wave
  int U = V * 16 + cl;        // global unit (col) this lane tracks

  // LDS-resident gates: i (m=0), g (m=2)  -- wave-private storage
#pragma unroll
  for (int kt = 0; kt < 8; ++kt) {
    WL[((w * 2 + 0) * 8 + kt) * 64 + lane] =
        fragB[(size_t)(((0 * 16 + V) * 8 + kt) * 64 + lane)];
    WL[((w * 2 + 1) * 8 + kt) * 64 + lane] =
        fragB[(size_t)(((2 * 16 + V) * 8 + kt) * 64 + lane)];
  }
  float Bi = bi[U], Bf = bf_[U], Bg = bg[U], Bo = bo[U];
  float c = 0.f, hl = 0.f;
  if (chunk0) { c = cstate[b * 256 + U]; hl = hstate[b * 256 + U]; }
  if (tid < 256) {
    float h0 = chunk0 ? hstate[b * 256 + tid] : 0.f;
    hb[tid] = __builtin_bit_cast(unsigned short, (f16)h0);
  }
  __syncthreads();

  const u32x4* pF = fragB + (size_t)(((1 * 16 + V) * 8) * 64 + lane);
  const u32x4* pO = fragB + (size_t)(((3 * 16 + V) * 8) * 64 + lane);
  unsigned int* xbW = XB + ((b * 2 + j) * 2) * 128 + (w * 16 + cl);
  unsigned int* xbR = XB + ((b * 2 + (1 - j)) * 2) * 128 + (w * 16 + cl);

  int p = 0;
#pragma unroll 1
  for (int t = 0; t < chunk_len; ++t) {
    int gt = chunk0 + t;
    // stream loads: f all 8, o first 4 (rest issued mid-step; caps live regs)
    u32x4 SF[8], SO[8];
#pragma unroll
    for (int kt = 0; kt < 8; ++kt) SF[kt] = pF[kt * 64];
#pragma unroll
    for (int kt = 0; kt < 4; ++kt) SO[kt] = pO[kt * 64];
    // A fragments (h broadcast) from LDS
    u32x4 A[8];
    const unsigned short* hbp = hb + p * 256 + (lane >> 4) * 8;
#pragma unroll
    for (int kt = 0; kt < 8; ++kt) A[kt] = *(const u32x4*)(hbp + kt * 32);
    // x-part (this lane's col, 4 gates)
    ushort4 xv = *(const ushort4*)(xw + (((size_t)t * 64 + b) * 256 + U) * 4);

    // gate i (LDS)
    f32x4 acc = {0.f, 0.f, 0.f, 0.f};
#pragma unroll
    for (int kt = 0; kt < 8; ++kt) {
      u32x4 wl = WL[((w * 2 + 0) * 8 + kt) * 64 + lane];
      acc = MFMA16(asf16x8(A[kt]), asf16x8(wl), acc);
    }
    float vi = acc[0];
    // gate g (LDS)
    acc = (f32x4){0.f, 0.f, 0.f, 0.f};
#pragma unroll
    for (int kt = 0; kt < 8; ++kt) {
      u32x4 wl = WL[((w * 2 + 1) * 8 + kt) * 64 + lane];
      acc = MFMA16(asf16x8(A[kt]), asf16x8(wl), acc);
    }
    float vg = acc[0];
    // gate f (streamed)
    acc = (f32x4){0.f, 0.f, 0.f, 0.f};
#pragma unroll
    for (int kt = 0; kt < 8; ++kt) acc = MFMA16(asf16x8(A[kt]), asf16x8(SF[kt]), acc);
    float vf = acc[0];
    // finish o stream, then o MFMAs
#pragma unroll
    for (int kt = 4; kt < 8; ++kt) SO[kt] = pO[kt * 64];
    acc = (f32x4){0.f, 0.f, 0.f, 0.f};
#pragma unroll
    for (int kt = 0; kt < 8; ++kt) acc = MFMA16(asf16x8(A[kt]), asf16x8(SO[kt]), acc);
    float vo = acc[0];

    // epilogue (all lanes redundantly; lane<16 are the writers)
    float pi_ = vi + tof(xv.x) + Bi;
    float pf_ = vf + tof(xv.y) + Bf;
    float pg_ = vg + tof(xv.z) + Bg;
    float po_ = vo + tof(xv.w) + Bo;
    float Gi = 1.f / (1.f + __expf(-pi_));
    float Gf = 1.f / (1.f + __expf(-pf_));
    float e2 = __expf(-2.f * fabsf(pg_));
    float Gg = copysignf((1.f - e2) / (1.f + e2), pg_);
    float Go = 1.f / (1.f + __expf(-po_));
    c = Gf * c + Gi * Gg;
    float ec = __expf(-2.f * fabsf(c));
    float tc = copysignf((1.f - ec) / (1.f + ec), c);
    float h = Go * tc;
    hl = h;
    unsigned short h16 = __builtin_bit_cast(unsigned short, (f16)h);
    int par = gt & 1;
    if (lane < 16) {
      out[((size_t)b * 2048 + gt) * 256 + U] = h;
      hb[(p ^ 1) * 256 + U] = h16;
      __hip_atomic_store(xbW + par * 128, ((unsigned)(gt + 1) << 16) | (unsigned)h16,
                         __ATOMIC_RELAXED, __HIP_MEMORY_SCOPE_AGENT);
      if (gt == 2047) {
        out[33554432 + b * 256 + U] = h;
        out[33554432 + 16384 + b * 256 + U] = c;
      }
      // spin for partner's h for the same step
      unsigned int v;
      int it = 0;
      do {
        if (it++) __builtin_amdgcn_s_sleep(2);
        v = __hip_atomic_load(xbR + par * 128, __ATOMIC_RELAXED,
                              __HIP_MEMORY_SCOPE_AGENT);
      } while ((v >> 16) != (unsigned)(gt + 1));
      hb[(p ^ 1) * 256 + ((1 - j) * 128 + w * 16 + cl)] = (unsigned short)(v & 0xFFFFu);
    }
    __syncthreads();
    p ^= 1;
  }
  if ((chunk0 + chunk_len < 2048) && lane < 16) {
    hstate[b * 256 + U] = hl;
    cstate[b * 256 + U] = c;
  }
}

extern "C" void kernel_launch(void* const* d_in, const int* in_sizes, int n_in,
                              void* d_out, int out_size, void* d_ws, size_t ws_size,
                              hipStream_t stream) {
  const float* X = (const float*)d_in[0];
  // dict order: X, W_ii, W_hi, b_i, W_if, W_hf, b_f, W_ig, W_hg, b_g, W_io, W_ho, b_o
  PtrPack pp;
  pp.p[0] = (const float*)d_in[1];   // W_ii
  pp.p[1] = (const float*)d_in[4];   // W_if
  pp.p[2] = (const float*)d_in[7];   // W_ig
  pp.p[3] = (const float*)d_in[10];  // W_io
  pp.p[4] = (const float*)d_in[2];   // W_hi
  pp.p[5] = (const float*)d_in[5];   // W_hf
  pp.p[6] = (const float*)d_in[8];   // W_hg
  pp.p[7] = (const float*)d_in[11];  // W_ho
  const float* bi  = (const float*)d_in[3];
  const float* bf_ = (const float*)d_in[6];
  const float* bg  = (const float*)d_in[9];
  const float* bo  = (const float*)d_in[12];
  float* out = (float*)d_out;

  char* ws = (char*)d_ws;
  f16*   wxT    = (f16*)ws;                        // 524288 B
  u32x4* fragB  = (u32x4*)(ws + 524288);           // 524288 B
  float* hstate = (float*)(ws + 1048576);          // 65536 B
  float* cstate = (float*)(ws + 1114112);          // 65536 B
  unsigned int* XB = (unsigned int*)(ws + 1179648);// 131072 B  (64b x 2j x 2par x 128)
  f16*   xwbuf  = (f16*)(ws + 1310720);            // sc * 131072 B

  long avail = (ws_size > 1310720) ? (long)(ws_size - 1310720) : 0;
  long sc = avail / 131072;
  sc = (sc / 16) * 16;            // k_gemm handles ragged 64-tiles via guards
  if (sc < 16) sc = 16;
  if (sc > 2048) sc = 2048;

  static const int RNN_SMEM = 131072 + 1024;
  hipFuncSetAttribute((const void*)k_rnn, hipFuncAttributeMaxDynamicSharedMemorySize,
                      RNN_SMEM);

  hipMemsetAsync(XB, 0, 131072, stream);  // clear exchange tags (replay safety)
  k_prep<<<dim3(4, 4, 4), 256, 0, stream>>>(pp, wxT);
  k_prepF<<<dim3(4, 4), 256, 0, stream>>>(pp, fragB);

  for (int s0 = 0; s0 < 2048; s0 += (int)sc) {
    int len = (int)((2048 - s0) < sc ? (2048 - s0) : sc);
    k_gemm<<<dim3(4, (len + 63) / 64, 64), 256, 0, stream>>>(X, wxT, xwbuf, s0, len);
    k_rnn<<<dim3(128), 512, RNN_SMEM, stream>>>(xwbuf, fragB, bi, bf_, bg, bo, out,
                                                hstate, cstate, XB, s0, len);
  }
}

// Round 9
// 4281.968 us; speedup vs baseline: 5.6172x; 1.0109x over previous
//
#include <hip/hip_runtime.h>

typedef _Float16 f16;
typedef _Float16 f16x8 __attribute__((ext_vector_type(8)));
typedef float    f32x4 __attribute__((ext_vector_type(4)));
typedef unsigned int u32x4 __attribute__((ext_vector_type(4)));

static __device__ __forceinline__ f16x8 asf16x8(u32x4 v) {
  return __builtin_bit_cast(f16x8, v);
}
static __device__ __forceinline__ float tof(unsigned short x) {
  return (float)__builtin_bit_cast(f16, x);
}

struct PtrPack { const float* p[8]; };

#define MFMA16(A, B, C) __builtin_amdgcn_mfma_f32_16x16x32_f16((A), (B), (C), 0, 0, 0)

// ---------------- prep A: 4x Wx (256x256) fp32 [k][u] -> f16 [u][k] for the GEMM ----
__global__ __launch_bounds__(256) void k_prep(PtrPack pp, f16* __restrict__ wxT) {
  int m = blockIdx.z, kt = blockIdx.y, ut = blockIdx.x;
  const float* src = pp.p[m];
  f16* dst = wxT + m * 65536;
  __shared__ f16 tile[64][66];
  int c = threadIdx.x & 63, r0 = threadIdx.x >> 6;
#pragma unroll
  for (int i = 0; i < 16; ++i) {
    int r = i * 4 + r0;
    tile[c][r] = (f16)src[(kt * 64 + r) * 256 + ut * 64 + c];
  }
  __syncthreads();
#pragma unroll
  for (int i = 0; i < 16; ++i) {
    int ul = i * 4 + r0;
    dst[(size_t)(ut * 64 + ul) * 256 + kt * 64 + c] = tile[ul][c];
  }
}

// ---------------- prep F: 4x Wh fp32 [k][u] -> MFMA B-fragment-major f16 -------------
// frag(ct,kt): 64 lanes x 16B; lane l holds Wh[k=kt*32+(l>>4)*8+e][col=ct*16+(l&15)].
__global__ __launch_bounds__(256) void k_prepF(PtrPack pp, u32x4* __restrict__ fragB) {
  int kb = blockIdx.x;   // k-block of 64 (0..3)
  int m  = blockIdx.y;   // gate 0..3 = i,f,g,o
  const float* src = pp.p[4 + m];
  int u = threadIdx.x;
  int ct = m * 16 + (u >> 4), cl = u & 15;
#pragma unroll
  for (int q = 0; q < 2; ++q) {
    int kt = kb * 2 + q;
#pragma unroll
    for (int l16 = 0; l16 < 4; ++l16) {
      union { f16 h[8]; u32x4 v; } pk;
#pragma unroll
      for (int e = 0; e < 8; ++e)
        pk.h[e] = (f16)src[(size_t)(kt * 32 + l16 * 8 + e) * 256 + u];
      fragB[(size_t)((ct * 8 + kt) * 64 + l16 * 16 + cl)] = pk.v;
    }
  }
}

// ---------------- X-part GEMM: XW (f16, layout [t][b][u][gate]) ----------------------
__global__ __launch_bounds__(256) void k_gemm(const float* __restrict__ X,
                                              const f16* __restrict__ wxT,
                                              f16* __restrict__ xw, int chunk0,
                                              int len) {
  int nblk = blockIdx.x;  // gate
  int mblk = blockIdx.y;
  int b    = blockIdx.z;
  __shared__ f16 Alds[64][48];
  __shared__ f16 Blds[256][48];
  int tid = threadIdx.x, wave = tid >> 6, lane = tid & 63;
  int l15 = lane & 15, l4 = lane >> 4;
  f32x4 acc[16];
#pragma unroll
  for (int i = 0; i < 16; ++i) acc[i] = (f32x4){0.f, 0.f, 0.f, 0.f};
  int tg = chunk0 + mblk * 64 + (tid >> 2);
  if (tg > 2047) tg = 2047;  // clamp (ragged tail) -- rows >= len never read
  const float* Xrow = X + ((size_t)b * 2048 + tg) * 256;
  const f16*   Bb = wxT + (size_t)nblk * 256 * 256;
  int arow = tid >> 2, akq = (tid & 3) * 8;

  for (int kk = 0; kk < 8; ++kk) {
    {
      const float* s = Xrow + kk * 32 + akq;
      float4 v0 = *(const float4*)s;
      float4 v1 = *(const float4*)(s + 4);
      union { f16 h[8]; uint4 q; } uq;
      uq.h[0] = (f16)v0.x; uq.h[1] = (f16)v0.y; uq.h[2] = (f16)v0.z; uq.h[3] = (f16)v0.w;
      uq.h[4] = (f16)v1.x; uq.h[5] = (f16)v1.y; uq.h[6] = (f16)v1.z; uq.h[7] = (f16)v1.w;
      *(uint4*)(&Alds[arow][akq]) = uq.q;
    }
    {
      const uint4* s = (const uint4*)(Bb + (size_t)tid * 256 + kk * 32);
      uint4* d = (uint4*)(&Blds[tid][0]);
      d[0] = s[0]; d[1] = s[1]; d[2] = s[2]; d[3] = s[3];
    }
    __syncthreads();
    f16x8 a = *(const f16x8*)(&Alds[wave * 16 + l15][l4 * 8]);
#pragma unroll
    for (int nt = 0; nt < 16; ++nt) {
      f16x8 bb = *(const f16x8*)(&Blds[nt * 16 + l15][l4 * 8]);
      acc[nt] = MFMA16(a, bb, acc[nt]);
    }
    __syncthreads();
  }
#pragma unroll
  for (int nt = 0; nt < 16; ++nt) {
#pragma unroll
    for (int r = 0; r < 4; ++r) {
      int trow = mblk * 64 + wave * 16 + l4 * 4 + r;
      int ucol = nt * 16 + l15;
      if (trow < len)
        xw[((size_t)trow * 64 + b) * 1024 + ucol * 4 + nblk] = (f16)acc[nt][r];
    }
  }
}

// ---------------- recurrent kernel: 4 wgs/batch, all-LDS weights, h-exchange ---------
// wg j of batch b owns units [j*64, j*64+64): 4 unit-tiles, wave w -> tile V=j*4+w,
// all 4 gates, 8 kt. Weights fully LDS-resident (128KB). Cross-wg: h via tagged
// relaxed agent-scope u32 payloads (tag16|h16), parity slots; wave w polls partner
// block w (w != j). Rotated kt order: own-block kts first -> poll overlaps own MFMAs.
__global__ __launch_bounds__(256, 1) void k_rnn(
    const f16* __restrict__ xw, const u32x4* __restrict__ fragB,
    const float* __restrict__ bi, const float* __restrict__ bf_,
    const float* __restrict__ bg, const float* __restrict__ bo,
    float* __restrict__ out, float* __restrict__ hstate, float* __restrict__ cstate,
    unsigned int* __restrict__ XB, int chunk0, int chunk_len) {
  extern __shared__ char smem[];
  u32x4* WL = (u32x4*)smem;                                // [4w][4m][8kt][64] 128KB
  unsigned short* hb = (unsigned short*)(smem + 131072);   // [2][256]
  int b = blockIdx.x & 63;
  int j = blockIdx.x >> 6;            // quarter 0..3 (pairs 64 apart: same XCD residue)
  int tid = threadIdx.x, w = tid >> 6, lane = tid & 63;
  int cl = lane & 15;
  int V = j * 4 + w;                  // global unit-tile
  int U = V * 16 + cl;                // global unit for lane<16

  // stage weights: wave w loads its 32 frags (4 gates x 8 kt) = 32KB
#pragma unroll
  for (int m = 0; m < 4; ++m)
#pragma unroll
    for (int kt = 0; kt < 8; ++kt)
      WL[((w * 4 + m) * 8 + kt) * 64 + lane] =
          fragB[(size_t)(((m * 16 + V) * 8 + kt) * 64 + lane)];

  float Bi = bi[U], Bf = bf_[U], Bg = bg[U], Bo = bo[U];
  float c = 0.f, hl = 0.f;
  if (chunk0 && lane < 16) { c = cstate[b * 256 + U]; hl = hstate[b * 256 + U]; }
  {
    float h0 = chunk0 ? hstate[b * 256 + tid] : 0.f;
    hb[tid] = __builtin_bit_cast(unsigned short, (f16)h0);
  }
  __syncthreads();

  int kb0 = j * 2;  // own k-tile base (this wg's h covers k in [j*64, j*64+64))
  unsigned int* xbW = XB + ((b * 4 + j) * 2) * 64 + (w * 16 + cl);
  unsigned int* xbR = XB + ((b * 4 + w) * 2) * 64 + lane;   // partner block w

  int p = 0;
#pragma unroll 1
  for (int t = 0; t < chunk_len; ++t) {
    int gt = chunk0 + t;
    bool do_poll = (w != j) && (t > 0);
    int par_r = (gt + 1) & 1;   // slot where partners stored tag == gt
    unsigned int pv = 0;
    if (do_poll)  // prefetch poll value before own-block compute
      pv = __hip_atomic_load(xbR + par_r * 64, __ATOMIC_RELAXED,
                             __HIP_MEMORY_SCOPE_AGENT);
    // x-part early (8B coalesced)
    ushort4 xv = *(const ushort4*)(xw + (((size_t)t * 64 + b) * 256 + U) * 4);

    // phase 1: own-block kts (hb[p] own 64 written before prev barrier)
    f32x4 acc[4] = {{0.f,0.f,0.f,0.f},{0.f,0.f,0.f,0.f},
                    {0.f,0.f,0.f,0.f},{0.f,0.f,0.f,0.f}};
    {
      const unsigned short* hbp = hb + p * 256 + (lane >> 4) * 8;
      u32x4 A0 = *(const u32x4*)(hbp + ((kb0 + 0) & 7) * 32);
      u32x4 A1 = *(const u32x4*)(hbp + ((kb0 + 1) & 7) * 32);
#pragma unroll
      for (int m = 0; m < 4; ++m) {
        u32x4 wl0 = WL[((w * 4 + m) * 8 + ((kb0 + 0) & 7)) * 64 + lane];
        u32x4 wl1 = WL[((w * 4 + m) * 8 + ((kb0 + 1) & 7)) * 64 + lane];
        acc[m] = MFMA16(asf16x8(A0), asf16x8(wl0), acc[m]);
        acc[m] = MFMA16(asf16x8(A1), asf16x8(wl1), acc[m]);
      }
    }
    // complete poll; fill partner block of hb[p]
    if (do_poll) {
      while (!__all((int)((pv >> 16) == (unsigned)gt))) {
        pv = __hip_atomic_load(xbR + par_r * 64, __ATOMIC_RELAXED,
                               __HIP_MEMORY_SCOPE_AGENT);
      }
      hb[p * 256 + w * 64 + lane] = (unsigned short)(pv & 0xFFFFu);
    }
    __syncthreads();  // barrier A: all partner h in hb[p]

    // phase 2: remaining 6 kts
    {
      const unsigned short* hbp = hb + p * 256 + (lane >> 4) * 8;
      u32x4 A2[6];
#pragma unroll
      for (int i = 0; i < 6; ++i)
        A2[i] = *(const u32x4*)(hbp + ((kb0 + 2 + i) & 7) * 32);
#pragma unroll
      for (int m = 0; m < 4; ++m) {
#pragma unroll
        for (int i = 0; i < 6; ++i) {
          u32x4 wl = WL[((w * 4 + m) * 8 + ((kb0 + 2 + i) & 7)) * 64 + lane];
          acc[m] = MFMA16(asf16x8(A2[i]), asf16x8(wl), acc[m]);
        }
      }
    }
    // epilogue (lane<16 are the writers; others compute redundantly)
    float pi_ = acc[0][0] + tof(xv.x) + Bi;
    float pf_ = acc[1][0] + tof(xv.y) + Bf;
    float pg_ = acc[2][0] + tof(xv.z) + Bg;
    float po_ = acc[3][0] + tof(xv.w) + Bo;
    float Gi = 1.f / (1.f + __expf(-pi_));
    float Gf = 1.f / (1.f + __expf(-pf_));
    float e2 = __expf(-2.f * fabsf(pg_));
    float Gg = copysignf((1.f - e2) / (1.f + e2), pg_);
    float Go = 1.f / (1.f + __expf(-po_));
    c = Gf * c + Gi * Gg;
    float ec = __expf(-2.f * fabsf(c));
    float tc = copysignf((1.f - ec) / (1.f + ec), c);
    float h = Go * tc;
    hl = h;
    unsigned short h16 = __builtin_bit_cast(unsigned short, (f16)h);
    if (lane < 16) {
      hb[(p ^ 1) * 256 + U] = h16;
      __hip_atomic_store(xbW + (gt & 1) * 64,
                         ((unsigned)(gt + 1) << 16) | (unsigned)h16,
                         __ATOMIC_RELAXED, __HIP_MEMORY_SCOPE_AGENT);
      out[((size_t)b * 2048 + gt) * 256 + U] = h;
      if (gt == 2047) {
        out[33554432 + b * 256 + U] = h;
        out[33554432 + 16384 + b * 256 + U] = c;
      }
    }
    __syncthreads();  // barrier B: own hb[p^1] visible for next phase 1
    p ^= 1;
  }
  if ((chunk0 + chunk_len < 2048) && lane < 16) {
    hstate[b * 256 + U] = hl;
    cstate[b * 256 + U] = c;
  }
}

extern "C" void kernel_launch(void* const* d_in, const int* in_sizes, int n_in,
                              void* d_out, int out_size, void* d_ws, size_t ws_size,
                              hipStream_t stream) {
  const float* X = (const float*)d_in[0];
  // dict order: X, W_ii, W_hi, b_i, W_if, W_hf, b_f, W_ig, W_hg, b_g, W_io, W_ho, b_o
  PtrPack pp;
  pp.p[0] = (const float*)d_in[1];   // W_ii
  pp.p[1] = (const float*)d_in[4];   // W_if
  pp.p[2] = (const float*)d_in[7];   // W_ig
  pp.p[3] = (const float*)d_in[10];  // W_io
  pp.p[4] = (const float*)d_in[2];   // W_hi
  pp.p[5] = (const float*)d_in[5];   // W_hf
  pp.p[6] = (const float*)d_in[8];   // W_hg
  pp.p[7] = (const float*)d_in[11];  // W_ho
  const float* bi  = (const float*)d_in[3];
  const float* bf_ = (const float*)d_in[6];
  const float* bg  = (const float*)d_in[9];
  const float* bo  = (const float*)d_in[12];
  float* out = (float*)d_out;

  char* ws = (char*)d_ws;
  f16*   wxT    = (f16*)ws;                        // 524288 B
  u32x4* fragB  = (u32x4*)(ws + 524288);           // 524288 B
  float* hstate = (float*)(ws + 1048576);          // 65536 B
  float* cstate = (float*)(ws + 1114112);          // 65536 B
  unsigned int* XB = (unsigned int*)(ws + 1179648);// 131072 B (64b x 4q x 2par x 64)
  f16*   xwbuf  = (f16*)(ws + 1310720);            // sc * 131072 B

  long avail = (ws_size > 1310720) ? (long)(ws_size - 1310720) : 0;
  long sc = avail / 131072;
  sc = (sc / 16) * 16;
  if (sc < 16) sc = 16;
  if (sc > 2048) sc = 2048;

  static const int RNN_SMEM = 131072 + 1024;
  hipFuncSetAttribute((const void*)k_rnn, hipFuncAttributeMaxDynamicSharedMemorySize,
                      RNN_SMEM);

  hipMemsetAsync(XB, 0, 131072, stream);  // clear exchange tags (replay safety)
  k_prep<<<dim3(4, 4, 4), 256, 0, stream>>>(pp, wxT);
  k_prepF<<<dim3(4, 4), 256, 0, stream>>>(pp, fragB);

  for (int s0 = 0; s0 < 2048; s0 += (int)sc) {
    int len = (int)((2048 - s0) < sc ? (2048 - s0) : sc);
    k_gemm<<<dim3(4, (len + 63) / 64, 64), 256, 0, stream>>>(X, wxT, xwbuf, s0, len);
    k_rnn<<<dim3(256), 256, RNN_SMEM, stream>>>(xwbuf, fragB, bi, bf_, bg, bo, out,
                                                hstate, cstate, XB, s0, len);
  }
}

// Round 10
// 4021.736 us; speedup vs baseline: 5.9807x; 1.0647x over previous
//
#include <hip/hip_runtime.h>

typedef _Float16 f16;
typedef _Float16 f16x8 __attribute__((ext_vector_type(8)));
typedef float    f32x4 __attribute__((ext_vector_type(4)));
typedef unsigned int u32x4 __attribute__((ext_vector_type(4)));

static __device__ __forceinline__ f16x8 asf16x8(u32x4 v) {
  return __builtin_bit_cast(f16x8, v);
}
static __device__ __forceinline__ float tof(unsigned short x) {
  return (float)__builtin_bit_cast(f16, x);
}

struct PtrPack { const float* p[8]; };

#define MFMA16(A, B, C) __builtin_amdgcn_mfma_f32_16x16x32_f16((A), (B), (C), 0, 0, 0)

// ---------------- prep A: 4x Wx (256x256) fp32 [k][u] -> f16 [u][k] for the GEMM ----
__global__ __launch_bounds__(256) void k_prep(PtrPack pp, f16* __restrict__ wxT) {
  int m = blockIdx.z, kt = blockIdx.y, ut = blockIdx.x;
  const float* src = pp.p[m];
  f16* dst = wxT + m * 65536;
  __shared__ f16 tile[64][66];
  int c = threadIdx.x & 63, r0 = threadIdx.x >> 6;
#pragma unroll
  for (int i = 0; i < 16; ++i) {
    int r = i * 4 + r0;
    tile[c][r] = (f16)src[(kt * 64 + r) * 256 + ut * 64 + c];
  }
  __syncthreads();
#pragma unroll
  for (int i = 0; i < 16; ++i) {
    int ul = i * 4 + r0;
    dst[(size_t)(ut * 64 + ul) * 256 + kt * 64 + c] = tile[ul][c];
  }
}

// ---------------- prep F: 4x Wh fp32 [k][u] -> MFMA B-fragment-major f16 -------------
// frag(ct,kt): 64 lanes x 16B; lane l holds Wh[k=kt*32+(l>>4)*8+e][col=ct*16+(l&15)].
__global__ __launch_bounds__(256) void k_prepF(PtrPack pp, u32x4* __restrict__ fragB) {
  int kb = blockIdx.x;   // k-block of 64 (0..3)
  int m  = blockIdx.y;   // gate 0..3 = i,f,g,o
  const float* src = pp.p[4 + m];
  int u = threadIdx.x;
  int ct = m * 16 + (u >> 4), cl = u & 15;
#pragma unroll
  for (int q = 0; q < 2; ++q) {
    int kt = kb * 2 + q;
#pragma unroll
    for (int l16 = 0; l16 < 4; ++l16) {
      union { f16 h[8]; u32x4 v; } pk;
#pragma unroll
      for (int e = 0; e < 8; ++e)
        pk.h[e] = (f16)src[(size_t)(kt * 32 + l16 * 8 + e) * 256 + u];
      fragB[(size_t)((ct * 8 + kt) * 64 + l16 * 16 + cl)] = pk.v;
    }
  }
}

// ---------------- X-part GEMM: XW (f16, layout [t][b][u][gate]) ----------------------
__global__ __launch_bounds__(256) void k_gemm(const float* __restrict__ X,
                                              const f16* __restrict__ wxT,
                                              f16* __restrict__ xw, int chunk0,
                                              int len) {
  int nblk = blockIdx.x;  // gate
  int mblk = blockIdx.y;
  int b    = blockIdx.z;
  __shared__ f16 Alds[64][48];
  __shared__ f16 Blds[256][48];
  int tid = threadIdx.x, wave = tid >> 6, lane = tid & 63;
  int l15 = lane & 15, l4 = lane >> 4;
  f32x4 acc[16];
#pragma unroll
  for (int i = 0; i < 16; ++i) acc[i] = (f32x4){0.f, 0.f, 0.f, 0.f};
  int tg = chunk0 + mblk * 64 + (tid >> 2);
  if (tg > 2047) tg = 2047;  // clamp (ragged tail) -- rows >= len never read
  const float* Xrow = X + ((size_t)b * 2048 + tg) * 256;
  const f16*   Bb = wxT + (size_t)nblk * 256 * 256;
  int arow = tid >> 2, akq = (tid & 3) * 8;

  for (int kk = 0; kk < 8; ++kk) {
    {
      const float* s = Xrow + kk * 32 + akq;
      float4 v0 = *(const float4*)s;
      float4 v1 = *(const float4*)(s + 4);
      union { f16 h[8]; uint4 q; } uq;
      uq.h[0] = (f16)v0.x; uq.h[1] = (f16)v0.y; uq.h[2] = (f16)v0.z; uq.h[3] = (f16)v0.w;
      uq.h[4] = (f16)v1.x; uq.h[5] = (f16)v1.y; uq.h[6] = (f16)v1.z; uq.h[7] = (f16)v1.w;
      *(uint4*)(&Alds[arow][akq]) = uq.q;
    }
    {
      const uint4* s = (const uint4*)(Bb + (size_t)tid * 256 + kk * 32);
      uint4* d = (uint4*)(&Blds[tid][0]);
      d[0] = s[0]; d[1] = s[1]; d[2] = s[2]; d[3] = s[3];
    }
    __syncthreads();
    f16x8 a = *(const f16x8*)(&Alds[wave * 16 + l15][l4 * 8]);
#pragma unroll
    for (int nt = 0; nt < 16; ++nt) {
      f16x8 bb = *(const f16x8*)(&Blds[nt * 16 + l15][l4 * 8]);
      acc[nt] = MFMA16(a, bb, acc[nt]);
    }
    __syncthreads();
  }
#pragma unroll
  for (int nt = 0; nt < 16; ++nt) {
#pragma unroll
    for (int r = 0; r < 4; ++r) {
      int trow = mblk * 64 + wave * 16 + l4 * 4 + r;
      int ucol = nt * 16 + l15;
      if (trow < len)
        xw[((size_t)trow * 64 + b) * 1024 + ucol * 4 + nblk] = (f16)acc[nt][r];
    }
  }
}

// ---------------- recurrent kernel: 1 wg/batch, 512 thr, MFMA, 3-channel delivery ----
// Wave w owns col-tiles ct0=w*2, ct1=w*2+1 (32 units). Gate i LDS-resident (128KB);
// gates f,g,o streamed from L2 kt-major, double-buffered S[2][6]. One barrier/step.
// No cross-wg communication (R8/R9 proved exchange costs ~3400cy/step, unhideable).
__global__ __launch_bounds__(512, 2) void k_rnn(
    const f16* __restrict__ xw, const u32x4* __restrict__ fragB,
    const float* __restrict__ bi, const float* __restrict__ bf_,
    const float* __restrict__ bg, const float* __restrict__ bo,
    float* __restrict__ out, float* __restrict__ hstate, float* __restrict__ cstate,
    int chunk0, int chunk_len) {
  extern __shared__ char smem[];
  u32x4* WL = (u32x4*)smem;                                // [8w][2ct][8kt][64] 128KB
  unsigned short* hb = (unsigned short*)(smem + 131072);   // [2][256]
  int b = blockIdx.x;
  int tid = threadIdx.x, w = tid >> 6, lane = tid & 63;
  int cl = lane & 15;
  int ctl = (lane >> 4) & 1;              // which of the wave's 2 cts this lane writes
  int U = (w * 2 + ctl) * 16 + cl;        // unit for epilogue/output
  bool act = lane < 32;

  // stage gate-i fragments (this wave's 2 cts x 8 kt = 16 KB)
#pragma unroll
  for (int ct = 0; ct < 2; ++ct)
#pragma unroll
    for (int kt = 0; kt < 8; ++kt)
      WL[((w * 2 + ct) * 8 + kt) * 64 + lane] =
          fragB[(size_t)(((0 * 16 + w * 2 + ct) * 8 + kt) * 64 + lane)];

  float Bi = bi[U], Bf = bf_[U], Bg = bg[U], Bo = bo[U];
  float c = 0.f, hl = 0.f;
  if (chunk0) { c = cstate[b * 256 + U]; hl = hstate[b * 256 + U]; }
  if (tid < 256) {
    float h0 = chunk0 ? hstate[b * 256 + tid] : 0.f;
    hb[tid] = __builtin_bit_cast(unsigned short, (f16)h0);
  }
  __syncthreads();

  // stream pointers (per-frag stride 64 u32x4 per kt)
  const u32x4* pF0 = fragB + (size_t)((16 + w * 2 + 0) * 8) * 64 + lane;
  const u32x4* pF1 = fragB + (size_t)((16 + w * 2 + 1) * 8) * 64 + lane;
  const u32x4* pG0 = fragB + (size_t)((32 + w * 2 + 0) * 8) * 64 + lane;
  const u32x4* pG1 = fragB + (size_t)((32 + w * 2 + 1) * 8) * 64 + lane;
  const u32x4* pO0 = fragB + (size_t)((48 + w * 2 + 0) * 8) * 64 + lane;
  const u32x4* pO1 = fragB + (size_t)((48 + w * 2 + 1) * 8) * 64 + lane;

  int p = 0;
#pragma unroll 1
  for (int t = 0; t < chunk_len; ++t) {
    int gt = chunk0 + t;
    // x-part for this lane's unit (8B coalesced)
    ushort4 xv = *(const ushort4*)(xw + (((size_t)t * 64 + b) * 256 + U) * 4);
    // prologue stream: kt=0 group
    u32x4 S[2][6];
    S[0][0] = pF0[0]; S[0][1] = pF1[0];
    S[0][2] = pG0[0]; S[0][3] = pG1[0];
    S[0][4] = pO0[0]; S[0][5] = pO1[0];

    f32x4 ai0 = {0.f,0.f,0.f,0.f}, ai1 = {0.f,0.f,0.f,0.f};
    f32x4 af0 = {0.f,0.f,0.f,0.f}, af1 = {0.f,0.f,0.f,0.f};
    f32x4 ag0 = {0.f,0.f,0.f,0.f}, ag1 = {0.f,0.f,0.f,0.f};
    f32x4 ao0 = {0.f,0.f,0.f,0.f}, ao1 = {0.f,0.f,0.f,0.f};

#pragma unroll
    for (int kt = 0; kt < 8; ++kt) {
      int cb = kt & 1, nb = (kt + 1) & 1;
      if (kt < 7) {  // issue next kt's stream group (hides under this kt's compute)
        S[nb][0] = pF0[(kt + 1) * 64]; S[nb][1] = pF1[(kt + 1) * 64];
        S[nb][2] = pG0[(kt + 1) * 64]; S[nb][3] = pG1[(kt + 1) * 64];
        S[nb][4] = pO0[(kt + 1) * 64]; S[nb][5] = pO1[(kt + 1) * 64];
      }
      // A fragment: h broadcast (lane's (l>>4) group supplies k = (l>>4)*8..+8)
      u32x4 A = *(const u32x4*)(hb + p * 256 + kt * 32 + (lane >> 4) * 8);
      // gate i from LDS
      u32x4 wi0 = WL[((w * 2 + 0) * 8 + kt) * 64 + lane];
      u32x4 wi1 = WL[((w * 2 + 1) * 8 + kt) * 64 + lane];
      ai0 = MFMA16(asf16x8(A), asf16x8(wi0), ai0);
      ai1 = MFMA16(asf16x8(A), asf16x8(wi1), ai1);
      // gates f,g,o from stream
      af0 = MFMA16(asf16x8(A), asf16x8(S[cb][0]), af0);
      af1 = MFMA16(asf16x8(A), asf16x8(S[cb][1]), af1);
      ag0 = MFMA16(asf16x8(A), asf16x8(S[cb][2]), ag0);
      ag1 = MFMA16(asf16x8(A), asf16x8(S[cb][3]), ag1);
      ao0 = MFMA16(asf16x8(A), asf16x8(S[cb][4]), ao0);
      ao1 = MFMA16(asf16x8(A), asf16x8(S[cb][5]), ao1);
    }

    // epilogue: all C rows equal (broadcast A); lane picks its ct via ctl
    float vi = ctl ? ai1[0] : ai0[0];
    float vf = ctl ? af1[0] : af0[0];
    float vg = ctl ? ag1[0] : ag0[0];
    float vo = ctl ? ao1[0] : ao0[0];
    float pi_ = vi + tof(xv.x) + Bi;
    float pf_ = vf + tof(xv.y) + Bf;
    float pg_ = vg + tof(xv.z) + Bg;
    float po_ = vo + tof(xv.w) + Bo;
    float Gi = 1.f / (1.f + __expf(-pi_));
    float Gf = 1.f / (1.f + __expf(-pf_));
    float e2 = __expf(-2.f * fabsf(pg_));
    float Gg = copysignf((1.f - e2) / (1.f + e2), pg_);
    float Go = 1.f / (1.f + __expf(-po_));
    c = Gf * c + Gi * Gg;
    float ec = __expf(-2.f * fabsf(c));
    float tc = copysignf((1.f - ec) / (1.f + ec), c);
    float h = Go * tc;
    hl = h;
    if (act) {
      unsigned short h16 = __builtin_bit_cast(unsigned short, (f16)h);
      hb[(p ^ 1) * 256 + U] = h16;
      out[((size_t)b * 2048 + gt) * 256 + U] = h;
      if (gt == 2047) {
        out[33554432 + b * 256 + U] = h;
        out[33554432 + 16384 + b * 256 + U] = c;
      }
    }
    __syncthreads();  // hb[p^1] complete for next step
    p ^= 1;
  }
  if ((chunk0 + chunk_len < 2048) && act) {
    hstate[b * 256 + U] = hl;
    cstate[b * 256 + U] = c;
  }
}

extern "C" void kernel_launch(void* const* d_in, const int* in_sizes, int n_in,
                              void* d_out, int out_size, void* d_ws, size_t ws_size,
                              hipStream_t stream) {
  const float* X = (const float*)d_in[0];
  // dict order: X, W_ii, W_hi, b_i, W_if, W_hf, b_f, W_ig, W_hg, b_g, W_io, W_ho, b_o
  PtrPack pp;
  pp.p[0] = (const float*)d_in[1];   // W_ii
  pp.p[1] = (const float*)d_in[4];   // W_if
  pp.p[2] = (const float*)d_in[7];   // W_ig
  pp.p[3] = (const float*)d_in[10];  // W_io
  pp.p[4] = (const float*)d_in[2];   // W_hi
  pp.p[5] = (const float*)d_in[5];   // W_hf
  pp.p[6] = (const float*)d_in[8];   // W_hg
  pp.p[7] = (const float*)d_in[11];  // W_ho
  const float* bi  = (const float*)d_in[3];
  const float* bf_ = (const float*)d_in[6];
  const float* bg  = (const float*)d_in[9];
  const float* bo  = (const float*)d_in[12];
  float* out = (float*)d_out;

  char* ws = (char*)d_ws;
  f16*   wxT    = (f16*)ws;                        // 524288 B
  u32x4* fragB  = (u32x4*)(ws + 524288);           // 524288 B
  float* hstate = (float*)(ws + 1048576);          // 65536 B
  float* cstate = (float*)(ws + 1114112);          // 65536 B
  f16*   xwbuf  = (f16*)(ws + 1179648);            // sc * 131072 B

  long avail = (ws_size > 1179648) ? (long)(ws_size - 1179648) : 0;
  long sc = avail / 131072;
  sc = (sc / 16) * 16;
  if (sc < 16) sc = 16;
  if (sc > 2048) sc = 2048;

  static const int RNN_SMEM = 131072 + 1024;
  hipFuncSetAttribute((const void*)k_rnn, hipFuncAttributeMaxDynamicSharedMemorySize,
                      RNN_SMEM);

  k_prep<<<dim3(4, 4, 4), 256, 0, stream>>>(pp, wxT);
  k_prepF<<<dim3(4, 4), 256, 0, stream>>>(pp, fragB);

  for (int s0 = 0; s0 < 2048; s0 += (int)sc) {
    int len = (int)((2048 - s0) < sc ? (2048 - s0) : sc);
    k_gemm<<<dim3(4, (len + 63) / 64, 64), 256, 0, stream>>>(X, wxT, xwbuf, s0, len);
    k_rnn<<<dim3(64), 512, RNN_SMEM, stream>>>(xwbuf, fragB, bi, bf_, bg, bo, out,
                                               hstate, cstate, s0, len);
  }
}